// Round 1
// baseline (190.570 us; speedup 1.0000x reference)
//
#include <hip/hip_runtime.h>
#include <math.h>

#define B_    4
#define C_    19
#define H_    320
#define W_    320
#define HW_   (H_*W_)
#define CHW_  (C_*HW_)
#define NPIX_ (B_*HW_)
#define NEPS_ 256
#define BIGI_ (1<<20)
#define INF_  0x3fffffff
#define IGN_  255

// ---------------- reduction helper (256-thread blocks = 4 waves) -------------
__device__ __forceinline__ void block_reduce_add_256(float v, float* out) {
  #pragma unroll
  for (int o = 32; o > 0; o >>= 1) v += __shfl_down(v, o);
  __shared__ float sh[4];
  int lane = threadIdx.x & 63, wid = threadIdx.x >> 6;
  if (lane == 0) sh[wid] = v;
  __syncthreads();
  if (threadIdx.x == 0) atomicAdd(out, sh[0] + sh[1] + sh[2] + sh[3]);
}

// ---------------- init: eps table (exact float sequence), hist, out ----------
__global__ void k_init(float* eps_tab, int* hist, float* out) {
  int t = threadIdx.x;
  if (t < 257) hist[t] = 0;
  if (t == 0) {
    float e = 1e-5f;
    for (int k = 0; k < NEPS_; ++k) { eps_tab[k] = e; e *= 1.2f; }
    out[0] = 0.f;
  }
}

// ---------------- row-wise 1D seed distance (Hillis-Steele min scans) --------
__global__ __launch_bounds__(W_) void k_rowdt(const int* __restrict__ tgt, int* __restrict__ R) {
  int b = blockIdx.x / H_, i = blockIdx.x % H_, j = threadIdx.x;
  const int* t = tgt + b * HW_;
  int tij = t[i*W_ + j];
  bool bnd = (tij == IGN_);
  if (i < H_-1) bnd |= (t[(i+1)*W_ + j] != tij);
  if (j < W_-1) bnd |= (t[i*W_ + j + 1] != tij);
  int s = bnd ? 0 : BIGI_;
  __shared__ int a[W_], c[W_];
  a[j] = s - j; c[j] = s + j;
  for (int ofs = 1; ofs < W_; ofs <<= 1) {
    __syncthreads();
    int av = (j >= ofs)      ? a[j-ofs] : INF_;
    int cv = (j + ofs < W_)  ? c[j+ofs] : INF_;
    __syncthreads();
    a[j] = min(a[j], av); c[j] = min(c[j], cv);
  }
  int Rv = min(a[j] + j, c[j] - j);
  R[(b*H_ + i)*W_ + j] = Rv;
}

// ---------------- column combine: dist = min_i max(|i-i0|, R_i) -------------
__global__ __launch_bounds__(H_) void k_coldt(const int* __restrict__ R, int* __restrict__ dist) {
  int b = blockIdx.x / W_, j = blockIdx.x % W_, tid = threadIdx.x;
  __shared__ int lev[9][H_];
  lev[0][tid] = R[(b*H_ + tid)*W_ + j];
  for (int l = 1; l <= 8; ++l) {
    int half = 1 << (l-1);
    __syncthreads();
    int other = (tid + half < H_) ? lev[l-1][tid + half] : INF_;
    lev[l][tid] = min(lev[l-1][tid], other);
  }
  __syncthreads();
  int i0 = tid;
  // feasible(d): min R over [i0-d, i0+d] (clamped) <= d
  auto feas = [&](int dd) -> bool {
    int lo = max(0, i0 - dd), hi = min(H_-1, i0 + dd);
    int len = hi - lo + 1;
    int l = 31 - __clz(len);
    int m = min(lev[l][lo], lev[l][hi - (1 << l) + 1]);
    return m <= dd;
  };
  int d;
  if (!feas(512)) d = B_ + 1 + H_ + W_;          // 645: no seed in image
  else {
    int lo = 0, hi = 512;
    while (lo < hi) { int mid = (lo + hi) >> 1; if (feas(mid)) hi = mid; else lo = mid + 1; }
    d = lo;
  }
  dist[(b*H_ + i0)*W_ + j] = d;
}

// ---------------- per-pixel softmax stats + target loss ---------------------
__global__ __launch_bounds__(256) void k_stats(const float* __restrict__ sl, const int* __restrict__ tgt,
                                               float* __restrict__ logZ, float* __restrict__ S,
                                               float* __restrict__ out) {
  int idx = blockIdx.x * 256 + threadIdx.x;
  int b = idx / HW_; int pix = idx - b * HW_;
  const float* base = sl + (size_t)b * CHW_ + pix;
  float x[C_]; float m = -1e30f;
  #pragma unroll
  for (int c = 0; c < C_; ++c) { x[c] = base[c*HW_]; m = fmaxf(m, x[c]); }
  float se = 0.f, E = 0.f;
  #pragma unroll
  for (int c = 0; c < C_; ++c) { float e = expf(x[c] - m); se += e; E += e * x[c]; }
  float lz = m + logf(se);
  logZ[idx] = lz;
  S[idx] = E / se - lz;
  int t = tgt[idx];
  float nll = (t != IGN_) ? (lz - base[t*HW_]) : 0.f;
  block_reduce_add_256(nll, out);
}

// ---------------- kl_map (tb+lr KL) + histogram over eps table --------------
__global__ __launch_bounds__(256) void k_klmap(const float* __restrict__ sl, const float* __restrict__ logZ,
                                               const float* __restrict__ S, float* __restrict__ kl_map,
                                               const float* __restrict__ eps_tab, int* __restrict__ hist) {
  __shared__ int sh[257];
  for (int e = threadIdx.x; e < 257; e += 256) sh[e] = 0;
  __syncthreads();
  int idx = blockIdx.x * 256 + threadIdx.x;
  int b = idx / HW_; int pix = idx - b * HW_;
  int i = pix / W_, j = pix - i * W_;
  const float* base = sl + (size_t)b * CHW_ + pix;
  float lz = logZ[idx], Sv = S[idx];
  float p[C_];
  #pragma unroll
  for (int c = 0; c < C_; ++c) p[c] = expf(base[c*HW_] - lz);
  float kl = 0.f;
  if (i < H_-1) {
    const float* bd = base + W_;
    float dot = 0.f;
    #pragma unroll
    for (int c = 0; c < C_; ++c) dot += p[c] * bd[c*HW_];
    kl += Sv - (dot - logZ[idx + W_]);
  }
  if (j < W_-1) {
    const float* br = base + 1;
    float dot = 0.f;
    #pragma unroll
    for (int c = 0; c < C_; ++c) dot += p[c] * br[c*HW_];
    kl += Sv - (dot - logZ[idx + 1]);
  }
  kl_map[idx] = kl;
  // g = #{k : e_k < kl}  (lower_bound; identical float compare as reference)
  int lo = 0, hi = NEPS_;
  while (lo < hi) { int mid = (lo + hi) >> 1; if (eps_tab[mid] < kl) lo = mid + 1; else hi = mid; }
  atomicAdd(&sh[lo], 1);
  __syncthreads();
  for (int e = threadIdx.x; e < 257; e += 256)
    if (sh[e]) atomicAdd(&hist[e], sh[e]);
}

// ---------------- eps selection: first k with count(>e_k) <= 5120 -----------
__global__ __launch_bounds__(256) void k_eps(const int* __restrict__ hist, const float* __restrict__ eps_tab,
                                             float* __restrict__ eps_sel) {
  __shared__ int h[257];
  __shared__ int bestk;
  int t = threadIdx.x;
  h[t] = hist[t];
  if (t == 0) { h[256] = hist[256]; bestk = NEPS_ - 1; }
  __syncthreads();
  int cnt = 0;
  for (int m = t + 1; m <= 256; ++m) cnt += h[m];
  if (cnt <= 5120) atomicMin(&bestk, t);
  __syncthreads();
  if (t == 0) eps_sel[0] = eps_tab[bestk];
}

// ---------------- final: mask dilation, direction, ce, border loss ----------
__global__ __launch_bounds__(256) void k_final(const float* __restrict__ sl, const int* __restrict__ dist,
                                               const float* __restrict__ kl_map, const float* __restrict__ logZ,
                                               const float* __restrict__ S, const float* __restrict__ eps_sel,
                                               float* __restrict__ out) {
  const int nx[9] = {1,-1,0,0,-1,1,-1,1,0};
  const int ny[9] = {0,0,-1,1,1,1,-1,-1,0};
  int b = blockIdx.z;
  int i0 = blockIdx.y * 16, j0 = blockIdx.x * 16;
  int tid = threadIdx.x; int li = tid >> 4, lj = tid & 15;
  __shared__ float kls[18][19];
  __shared__ int   dss[18][19];
  float eps = eps_sel[0];
  for (int e = tid; e < 18*18; e += 256) {
    int r = e / 18, cc = e - r * 18;
    int gi = i0 - 1 + r, gj = j0 - 1 + cc;
    bool ok = (gi >= 0 && gi < H_ && gj >= 0 && gj < W_);
    int gidx = (b*H_ + gi)*W_ + gj;
    kls[r][cc] = ok ? kl_map[gidx] : -1e30f;
    dss[r][cc] = ok ? dist[gidx] : 100000;
  }
  __syncthreads();
  int i = i0 + li, j = j0 + lj;
  int idx = (b*H_ + i)*W_ + j;
  bool mask = false;
  #pragma unroll
  for (int dr = 0; dr < 3; ++dr)
    #pragma unroll
    for (int dc = 0; dc < 3; ++dc)
      mask |= (kls[li+dr][lj+dc] > eps);
  int best = INF_, dir = 0;
  #pragma unroll
  for (int k = 0; k < 9; ++k) {
    int r = dss[li+1+nx[k]][lj+1+ny[k]];
    if (r < best) { best = r; dir = k; }
  }
  bool valid = mask && (dir != 8);
  float term = 0.f;
  if (valid) {
    int label = min(dir, 7);
    const float* basec = sl + (size_t)b * CHW_ + i*W_ + j;
    float lzc = logZ[idx];
    float xc[C_];
    #pragma unroll
    for (int c = 0; c < C_; ++c) xc[c] = basec[c*HW_];
    float klmax = -1e30f, kll = 0.f, klb[8];
    #pragma unroll
    for (int k = 0; k < 8; ++k) {
      int ic = min(max(i + nx[k], 0), H_-1);
      int jc = min(max(j + ny[k], 0), W_-1);
      int nidx = (b*H_ + ic)*W_ + jc;
      float lzn = logZ[nidx], Sn = S[nidx];
      const float* bn = sl + (size_t)b * CHW_ + ic*W_ + jc;
      float dot = 0.f;
      #pragma unroll
      for (int c = 0; c < C_; ++c) dot += expf(bn[c*HW_] - lzn) * xc[c];
      float kv = Sn - dot + lzc;
      klb[k] = kv;
      klmax = fmaxf(klmax, kv);
      if (k == label) kll = kv;
    }
    float sume = 0.f;
    #pragma unroll
    for (int k = 0; k < 8; ++k) sume += expf(klb[k] - klmax);
    float ce = klmax + logf(sume) - kll;
    float dv = (float)dss[li+1][lj+1];
    term = ce + fminf(dv, 20.f) * (1.f / 20.f);
  }
  block_reduce_add_256(term, out);
}

// ---------------- launch -----------------------------------------------------
extern "C" void kernel_launch(void* const* d_in, const int* in_sizes, int n_in,
                              void* d_out, int out_size, void* d_ws, size_t ws_size,
                              hipStream_t stream) {
  const float* sl  = (const float*)d_in[0];
  const int*   tgt = (const int*)d_in[1];
  float* out = (float*)d_out;

  float* logZ    = (float*)d_ws;
  float* S       = logZ + NPIX_;
  float* kl_map  = S + NPIX_;
  int*   dist    = (int*)(kl_map + NPIX_);
  int*   R       = dist + NPIX_;
  float* eps_tab = (float*)(R + NPIX_);
  int*   hist    = (int*)(eps_tab + NEPS_);
  float* eps_sel = (float*)(hist + 258);

  k_init <<<1, 320, 0, stream>>>(eps_tab, hist, out);
  k_rowdt<<<B_*H_, W_, 0, stream>>>(tgt, R);
  k_coldt<<<B_*W_, H_, 0, stream>>>(R, dist);
  k_stats<<<NPIX_/256, 256, 0, stream>>>(sl, tgt, logZ, S, out);
  k_klmap<<<NPIX_/256, 256, 0, stream>>>(sl, logZ, S, kl_map, eps_tab, hist);
  k_eps  <<<1, 256, 0, stream>>>(hist, eps_tab, eps_sel);
  dim3 gf(W_/16, H_/16, B_);
  k_final<<<gf, 256, 0, stream>>>(sl, dist, kl_map, logZ, S, eps_sel, out);
}